// Round 15
// baseline (300.015 us; speedup 1.0000x reference)
//
#include <hip/hip_runtime.h>

#define DEV __device__ __forceinline__

using f32x4 = __attribute__((ext_vector_type(4))) float;
using f16x8 = __attribute__((ext_vector_type(8))) _Float16;
using f16x4 = __attribute__((ext_vector_type(4))) _Float16;

constexpr int Bc = 8, Tc = 2048, Ec = 1024, Hc = 1024;
constexpr int Mc = Bc * Tc;    // 16384 total rows
constexpr int SLOT = 256 * 32; // elements per 16KB slice

DEV f32x4 mfma16(f16x8 a, f16x8 b, f32x4 c) {
    return __builtin_amdgcn_mfma_f32_16x16x32_f16(a, b, c, 0, 0, 0);
}
DEV unsigned short f16bits(float f) { return __builtin_bit_cast(unsigned short, (_Float16)f); }
DEV float f16val(unsigned short u) { return (float)__builtin_bit_cast(_Float16, u); }

// async global->LDS, 16B per lane. LDS dest must be wave-uniform base; HW adds lane*16.
DEV void gload16(const _Float16* g, _Float16* l) {
    __builtin_amdgcn_global_load_lds(
        (const __attribute__((address_space(1))) unsigned int*)g,
        (__attribute__((address_space(3))) unsigned int*)l, 16, 0, 0);
}

// Paired-row swizzled LDS slice layout (256x32 f16 = 16KB):
// LDS row r (128B) holds tile-rows {2r, 2r+1}; the 8 16B slots within row r
// are XOR-permuted by (r&7).  Verified 0 bank conflicts (rounds 5-14).
DEV int swz_off(int R, int lk) {
    return ((R >> 1) << 6) + ((((((R & 1) << 2) | lk) ^ ((R >> 1) & 7))) << 3);
}

// ---------------------------------------------------------------------------
// prep_x: f32 x -> f16
// ---------------------------------------------------------------------------
__global__ __launch_bounds__(256) void prep_x(const float* __restrict__ x,
                                              _Float16* __restrict__ xf, int n) {
    int i = (blockIdx.x * 256 + threadIdx.x) * 4;
    if (i >= n) return;
    f32x4 v = *reinterpret_cast<const f32x4*>(x + i);
    f16x4 h;
#pragma unroll
    for (int j = 0; j < 4; j++) h[j] = (_Float16)v[j];
    *reinterpret_cast<f16x4*>(xf + i) = h;
}

// ---------------------------------------------------------------------------
// prep_w: transpose W[e][n] -> WT[n][e], f16.
// Wall[3072][1024]: rows [0,1024)=Wq, [1024,2048)=Wk, [2048,3072)=Wv.
// ---------------------------------------------------------------------------
__global__ __launch_bounds__(256) void prep_w(const float* __restrict__ wq,
                                              const float* __restrict__ wk,
                                              const float* __restrict__ wv,
                                              _Float16* __restrict__ wall) {
    __shared__ float tile[32][33];
    const int z = blockIdx.z;
    const float* src = (z == 0) ? wq : (z == 1) ? wk : wv;
    _Float16* dh = wall + (size_t)z * 1024 * Ec;
    const int n0 = blockIdx.x * 32, e0 = blockIdx.y * 32;
    const int tx = threadIdx.x & 31, ty = threadIdx.x >> 5;  // 32 x 8
#pragma unroll
    for (int j = 0; j < 32; j += 8)
        tile[ty + j][tx] = src[(size_t)(e0 + ty + j) * Hc + n0 + tx];
    __syncthreads();
#pragma unroll
    for (int j = 0; j < 32; j += 8)
        dh[(size_t)(n0 + ty + j) * Ec + e0 + tx] = (_Float16)tile[tx][ty + j];
}

// ---------------------------------------------------------------------------
// gemm_body: 256x256 tile, FOUR waves (2x2, each owning a 128x128 quadrant),
// 256 threads, 1 wave/SIMD (launch_bounds(256,1): acc[8][8]=256 VGPRs + ~100
// working regs ~ 360 <= 512).  Rationale (round-14 analysis): the 8-wave
// 128x64-per-wave shape is LDS-read-bandwidth-bound (96KB frag reads per
// CU-slot vs 310 cyc of MFMA).  128x128 waves read 64KB per CU-slot for the
// same MFMA work (A8+B8 b128 reads -> 64 MFMA per wave per slot).
// Schedule = round-10/13 (best measured): BK=32 slots, ring-3 LDS (96 KiB),
// ONE barrier per slot:
//   { 16 ds_read (bfr then af); stage(P+2) -> slot (P+2)%3 (8 gloads);
//     setprio(1); 64 MFMA; setprio(0); vmcnt(8); s_barrier }
// Counted vmcnt(8): stage(P+2)'s 8 loads may stay in flight; stage(P+1)
// (issued in slot P-1) proven complete at the slot exit.
// Per-element K accumulation order identical to round 13 (bit-identical out).
// EPI: 0 = f16 out, N=2048: Q (gn<1024) / K (gn>=1024)
//      1 = f16 transposed store Vt[b][n][t]
//      2 = f16 causal energy * 1/sqrt(dk)
//      3 = f32 row-major (PV), nkt = (mt+1)*8
// ---------------------------------------------------------------------------
template <int EPI>
DEV void gemm_body(int bx, int mt, int z,
                   const _Float16* __restrict__ Ah, const _Float16* __restrict__ Bh,
                   void* __restrict__ out0, void* __restrict__ out2,
                   const int* __restrict__ dkp,
                   int lda, int ldb, size_t aBS, size_t bBS, size_t oBS, int nkt,
                   _Float16* sAb, _Float16* sBb) {
    if (EPI == 3) nkt = (mt + 1) * 8;  // causal K extent (256-row bands)

    Ah += (size_t)z * aBS;
    Bh += (size_t)z * bBS;

    const float scale = (EPI == 2) ? (1.0f / sqrtf((float)*dkp)) : 1.0f;

    const int tid = threadIdx.x;
    const int wave = tid >> 6, lane = tid & 63;
    const int lr = lane & 15, lk = lane >> 4;
    const int wm = wave >> 1, wn2 = wave & 1;  // 2x2 wave grid; wave = 128x128
    const int m0 = mt * 256, n0 = bx * 256;

    // staging constants (inverse-swizzled global source, linear LDS dest):
    const int so = (lane & 7) ^ (lane >> 3);
    const int strow = 2 * (lane >> 3) + (so >> 2);
    const int stcol = (so & 3) * 8;
    // each wave stages 4 A-groups + 4 B-groups (16 groups of 16 rows each)
    size_t aoff[4], boff[4];
#pragma unroll
    for (int l = 0; l < 4; l++) {
        aoff[l] = (size_t)(m0 + (wave * 4 + l) * 16 + strow) * lda + stcol;
        boff[l] = (size_t)(n0 + (wave * 4 + l) * 16 + strow) * ldb + stcol;
    }

    auto stage = [&](int sv, int slot) {
        const int kk = sv * 32;
        _Float16* dA = sAb + slot * SLOT;
        _Float16* dB = sBb + slot * SLOT;
#pragma unroll
        for (int l = 0; l < 4; l++) {
            gload16(Ah + aoff[l] + kk, dA + (wave * 4 + l) * 512);
            gload16(Bh + boff[l] + kk, dB + (wave * 4 + l) * 512);
        }
    };

    f32x4 acc[8][8] = {};

    // prologue: slots 0 and 1 in flight; gate slot 0 (allow slot 1's 8 loads)
    stage(0, 0);
    stage(1, 1);
    asm volatile("s_waitcnt vmcnt(8)" ::: "memory");
    __builtin_amdgcn_s_barrier();

    int rP = 0;  // P % 3
    for (int P = 0; P < nkt; ++P) {
        const _Float16* cA = sAb + rP * SLOT;
        const _Float16* cB = sBb + rP * SLOT;
        f16x8 af[8], bfr[8];

        // B frags first so the first MFMA's operands arrive earliest
#pragma unroll
        for (int nj = 0; nj < 8; nj++)
            bfr[nj] = *reinterpret_cast<const f16x8*>(
                &cB[swz_off(wn2 * 128 + nj * 16 + lr, lk)]);
#pragma unroll
        for (int mi = 0; mi < 8; mi++)
            af[mi] = *reinterpret_cast<const f16x8*>(
                &cA[swz_off(wm * 128 + mi * 16 + lr, lk)]);

        int rs = rP + 2; if (rs >= 3) rs -= 3;
        if (P + 2 < nkt) stage(P + 2, rs);

        __builtin_amdgcn_s_setprio(1);
#pragma unroll
        for (int mi = 0; mi < 8; mi++)
#pragma unroll
            for (int nj = 0; nj < 8; nj++)
                acc[mi][nj] = mfma16(af[mi], bfr[nj], acc[mi][nj]);
        __builtin_amdgcn_s_setprio(0);

        // slot-exit gate: stage(P+1) must be complete (counted; never 0 in
        // steady state).  Skip entirely on the last slot.
        if (P + 2 < nkt) {
            asm volatile("s_waitcnt vmcnt(8)" ::: "memory");
            __builtin_amdgcn_s_barrier();
        } else if (P + 1 < nkt) {
            asm volatile("s_waitcnt vmcnt(0)" ::: "memory");
            __builtin_amdgcn_s_barrier();
        }
        if (++rP == 3) rP = 0;
    }

#pragma unroll
    for (int mi = 0; mi < 8; mi++)
#pragma unroll
        for (int nj = 0; nj < 8; nj++) {
            const int gn = n0 + wn2 * 128 + nj * 16 + lr;
            if (EPI == 1) {
                const int gm0 = m0 + wm * 128 + mi * 16 + lk * 4;
                const int bb = gm0 >> 11, t = gm0 & (Tc - 1);
                f16x4 pk;
#pragma unroll
                for (int r = 0; r < 4; r++) pk[r] = (_Float16)acc[mi][nj][r];
                *reinterpret_cast<f16x4*>(
                    &((_Float16*)out0)[((size_t)(bb * Hc + gn)) * Tc + t]) = pk;
            } else if (EPI == 0) {
                _Float16* od = (gn < 1024) ? (_Float16*)out0 : (_Float16*)out2;
                const int cc = gn & 1023;
#pragma unroll
                for (int r = 0; r < 4; r++) {
                    const int gm = m0 + wm * 128 + mi * 16 + lk * 4 + r;
                    od[(size_t)gm * Hc + cc] = (_Float16)acc[mi][nj][r];
                }
            } else {
#pragma unroll
                for (int r = 0; r < 4; r++) {
                    const int gm = m0 + wm * 128 + mi * 16 + lk * 4 + r;
                    const float v = acc[mi][nj][r];
                    if (EPI == 2) {
                        const float e = (gn > gm) ? -INFINITY : v * scale;
                        ((unsigned short*)out0)[(size_t)z * oBS + (size_t)gm * Tc + gn] =
                            f16bits(e);
                    } else {
                        ((float*)out0)[(size_t)z * oBS + (size_t)gm * Hc + gn] = v;
                    }
                }
            }
        }
}

// ---------------------------------------------------------------------------
// k_qkv: QK-projection (512 blocks) + V-projection (256 blocks), 32 slots.
// launch_bounds(256,1): acc[8][8] needs ~360 regs/wave — 1 wave/SIMD by
// design.  Do NOT raise min-waves (round 8: reg starvation = 9x slowdown).
// ---------------------------------------------------------------------------
__global__ __launch_bounds__(256, 1) void k_qkv(
        const _Float16* __restrict__ Xf, const _Float16* __restrict__ Wall,
        _Float16* __restrict__ Qf, _Float16* __restrict__ Kf,
        _Float16* __restrict__ Vt, const int* __restrict__ dkp) {
    __shared__ _Float16 sA[3][SLOT];  // 48 KiB
    __shared__ _Float16 sB[3][SLOT];  // 48 KiB
    const int i = blockIdx.x;
    if (i < 512) {
        // QK proj: bijective XCD chunking over the (8 x 64) tile grid
        const int w = (i & 7) * 64 + (i >> 3);
        const int by = w >> 3, bx = w & 7;
        gemm_body<0>(bx, by, 0, Xf, Wall, Qf, Kf, dkp,
                     Ec, Ec, 0, 0, 0, 32, sA[0], sB[0]);
    } else {
        const int j = i - 512;  // V proj: (4 x 64) tile grid
        gemm_body<1>(j & 3, j >> 2, 0, Xf, Wall + (size_t)2048 * Ec,
                     Vt, nullptr, dkp, Ec, Ec, 0, 0, 0, 32, sA[0], sB[0]);
    }
}

// ---------------------------------------------------------------------------
// k_energy: 288 causal tiles (36 per batch), single-term f16, 32 slots.
// ---------------------------------------------------------------------------
__global__ __launch_bounds__(256, 1) void k_energy(
        const _Float16* __restrict__ Qf, const _Float16* __restrict__ Kf,
        unsigned short* __restrict__ S, const int* __restrict__ dkp) {
    __shared__ _Float16 sA[3][SLOT];
    __shared__ _Float16 sB[3][SLOT];
    const int i = blockIdx.x;
    const int b = i / 36;
    int t = i - b * 36;
    int by = 0;
    while (t >= by + 1) { t -= by + 1; by++; }  // triangle decode: bx=t <= by
    gemm_body<2>(t, by, b, Qf, Kf, S, nullptr, dkp,
                 Hc, Hc, (size_t)Tc * Hc, (size_t)Tc * Hc, (size_t)Tc * Tc, 32,
                 sA[0], sB[0]);
}

// ---------------------------------------------------------------------------
// k_pv: PV, grid (4, 8, batch); nkt = (by+1)*8 inside body.  P is f16.
// ---------------------------------------------------------------------------
__global__ __launch_bounds__(256, 1) void k_pv(
        const _Float16* __restrict__ S, const _Float16* __restrict__ Vt,
        float* __restrict__ out, const int* __restrict__ dkp) {
    __shared__ _Float16 sA[3][SLOT];
    __shared__ _Float16 sB[3][SLOT];
    gemm_body<3>(blockIdx.x, blockIdx.y, blockIdx.z, S, Vt, out, nullptr, dkp,
                 Tc, Tc, (size_t)Tc * Tc, (size_t)Hc * Tc, (size_t)Tc * Hc, 0,
                 sA[0], sB[0]);
}

// ---------------------------------------------------------------------------
// softmax_k: one block per (b,q) row.  f16 logits in, f16 P out (in place).
// Threads beyond the tile-aligned causal extent skip loads/stores (PV never
// reads those cols) but participate in reductions.
// ---------------------------------------------------------------------------
__global__ __launch_bounds__(256) void softmax_k(unsigned short* __restrict__ S) {
    const int q = blockIdx.x & (Tc - 1);
    const int b = blockIdx.x >> 11;
    const int tid = threadIdx.x;
    const int c0 = tid * 8;
    const int limit = ((q >> 8) + 1) << 8;  // tile-aligned causal extent
    const bool active = c0 < limit;
    unsigned short* row = S + ((size_t)b * Tc + q) * Tc;

    float v[8];
    if (active) {
        uint4 raw = *reinterpret_cast<const uint4*>(row + c0);
        unsigned u[4] = {raw.x, raw.y, raw.z, raw.w};
#pragma unroll
        for (int p = 0; p < 4; p++) {
            v[2 * p]     = f16val((unsigned short)(u[p] & 0xFFFFu));
            v[2 * p + 1] = f16val((unsigned short)(u[p] >> 16));
        }
#pragma unroll
        for (int i = 0; i < 8; i++)
            if (c0 + i > q) v[i] = -INFINITY;
    } else {
#pragma unroll
        for (int i = 0; i < 8; i++) v[i] = -INFINITY;
    }

    float m = v[0];
#pragma unroll
    for (int i = 1; i < 8; i++) m = fmaxf(m, v[i]);
#pragma unroll
    for (int off = 1; off < 64; off <<= 1) m = fmaxf(m, __shfl_xor(m, off));
    __shared__ float red[4];
    if ((tid & 63) == 0) red[tid >> 6] = m;
    __syncthreads();
    m = fmaxf(fmaxf(red[0], red[1]), fmaxf(red[2], red[3]));

    float e[8], s = 0.f;
#pragma unroll
    for (int i = 0; i < 8; i++) {
        e[i] = __expf(v[i] - m);  // exp(-inf)=0
        s += e[i];
    }
#pragma unroll
    for (int off = 1; off < 64; off <<= 1) s += __shfl_xor(s, off);
    __syncthreads();
    if ((tid & 63) == 0) red[tid >> 6] = s;
    __syncthreads();
    s = red[0] + red[1] + red[2] + red[3];
    const float inv = 1.0f / s;

    if (active) {
        unsigned o[4];
#pragma unroll
        for (int p = 0; p < 4; p++) {
            unsigned short a = f16bits(e[2 * p] * inv);
            unsigned short bb = f16bits(e[2 * p + 1] * inv);
            o[p] = (unsigned)a | ((unsigned)bb << 16);
        }
        uint4 w; w.x = o[0]; w.y = o[1]; w.z = o[2]; w.w = o[3];
        *reinterpret_cast<uint4*>(row + c0) = w;
    }
}

// ---------------------------------------------------------------------------
extern "C" void kernel_launch(void* const* d_in, const int* in_sizes, int n_in,
                              void* d_out, int out_size, void* d_ws, size_t ws_size,
                              hipStream_t stream) {
    const float* x  = (const float*)d_in[0];
    const float* Wq = (const float*)d_in[1];
    const float* Wk = (const float*)d_in[2];
    const float* Wv = (const float*)d_in[3];
    const int*   dk = (const int*)d_in[4];
    float* out = (float*)d_out;
    char* ws = (char*)d_ws;

    const size_t SZ_XE = (size_t)Mc * Ec * 2;  // 32 MiB (f16 [16384][1024])
    const size_t SZ_W  = (size_t)Ec * Hc * 2;  // 2 MiB

    // Layout: persistent buffers first, prep buffers last so S can alias them.
    size_t o = 0;
    auto nxt = [&](size_t bytes) { void* p = ws + o; o += bytes; return p; };
    _Float16* Qf   = (_Float16*)nxt(SZ_XE);
    _Float16* Kf   = (_Float16*)nxt(SZ_XE);
    _Float16* Vt   = (_Float16*)nxt(SZ_XE);
    _Float16* Xf   = (_Float16*)nxt(SZ_XE);
    _Float16* Wall = (_Float16*)nxt(3 * SZ_W);  // [3072][1024] = Wq|Wk|Wv, transposed
    // S: all-batch f16 [8][2048][2048] = 64 MiB, aliases Xf+Wall+beyond
    // (Xf and Wall are dead once k_qkv completes; k_energy is stream-ordered).
    unsigned short* S = (unsigned short*)Xf;
    (void)ws_size; (void)in_sizes; (void)n_in; (void)out_size;

    prep_x<<<(Mc * Ec / 4 + 255) / 256, 256, 0, stream>>>(x, Xf, Mc * Ec);
    prep_w<<<dim3(32, 32, 3), 256, 0, stream>>>(Wq, Wk, Wv, Wall);

    // Q, K, V projections: single-term f16, K=1024
    k_qkv<<<768, 256, 0, stream>>>(Xf, Wall, Qf, Kf, Vt, dk);

    // energy: 288 causal tiles, f16 logits
    k_energy<<<288, 256, 0, stream>>>(Qf, Kf, (unsigned short*)S, dk);

    softmax_k<<<Bc * Tc, 256, 0, stream>>>((unsigned short*)S);

    // PV: nkt=(by+1)*8 per tile (P beyond causal edge is 0)
    k_pv<<<dim3(4, 8, Bc), 256, 0, stream>>>((const _Float16*)S, Vt, out, dk);
}

// Round 16
// 293.570 us; speedup vs baseline: 1.0220x; 1.0220x over previous
//
#include <hip/hip_runtime.h>

#define DEV __device__ __forceinline__

using f32x4 = __attribute__((ext_vector_type(4))) float;
using f16x8 = __attribute__((ext_vector_type(8))) _Float16;
using f16x4 = __attribute__((ext_vector_type(4))) _Float16;

constexpr int Bc = 8, Tc = 2048, Ec = 1024, Hc = 1024;
constexpr int Mc = Bc * Tc;      // 16384 total rows
constexpr int SLOT  = 256 * 32;  // 16KB slice
constexpr int SLOTA = 128 * 32;  // 8KB slice (4-wave body A)

DEV f32x4 mfma16(f16x8 a, f16x8 b, f32x4 c) {
    return __builtin_amdgcn_mfma_f32_16x16x32_f16(a, b, c, 0, 0, 0);
}
DEV unsigned short f16bits(float f) { return __builtin_bit_cast(unsigned short, (_Float16)f); }
DEV float f16val(unsigned short u) { return (float)__builtin_bit_cast(_Float16, u); }

// async global->LDS, 16B per lane. LDS dest must be wave-uniform base; HW adds lane*16.
DEV void gload16(const _Float16* g, _Float16* l) {
    __builtin_amdgcn_global_load_lds(
        (const __attribute__((address_space(1))) unsigned int*)g,
        (__attribute__((address_space(3))) unsigned int*)l, 16, 0, 0);
}

// Paired-row swizzled LDS slice layout (R x 32 f16):
// LDS row r (128B) holds tile-rows {2r, 2r+1}; the 8 16B slots within row r
// are XOR-permuted by (r&7).  Verified 0 bank conflicts (rounds 5-15).
DEV int swz_off(int R, int lk) {
    return ((R >> 1) << 6) + ((((((R & 1) << 2) | lk) ^ ((R >> 1) & 7))) << 3);
}

// ---------------------------------------------------------------------------
// prep_x: f32 x -> f16
// ---------------------------------------------------------------------------
__global__ __launch_bounds__(256) void prep_x(const float* __restrict__ x,
                                              _Float16* __restrict__ xf, int n) {
    int i = (blockIdx.x * 256 + threadIdx.x) * 4;
    if (i >= n) return;
    f32x4 v = *reinterpret_cast<const f32x4*>(x + i);
    f16x4 h;
#pragma unroll
    for (int j = 0; j < 4; j++) h[j] = (_Float16)v[j];
    *reinterpret_cast<f16x4*>(xf + i) = h;
}

// ---------------------------------------------------------------------------
// prep_w: transpose W[e][n] -> WT[n][e], f16.
// Wall[3072][1024]: rows [0,1024)=Wq, [1024,2048)=Wk, [2048,3072)=Wv.
// ---------------------------------------------------------------------------
__global__ __launch_bounds__(256) void prep_w(const float* __restrict__ wq,
                                              const float* __restrict__ wk,
                                              const float* __restrict__ wv,
                                              _Float16* __restrict__ wall) {
    __shared__ float tile[32][33];
    const int z = blockIdx.z;
    const float* src = (z == 0) ? wq : (z == 1) ? wk : wv;
    _Float16* dh = wall + (size_t)z * 1024 * Ec;
    const int n0 = blockIdx.x * 32, e0 = blockIdx.y * 32;
    const int tx = threadIdx.x & 31, ty = threadIdx.x >> 5;  // 32 x 8
#pragma unroll
    for (int j = 0; j < 32; j += 8)
        tile[ty + j][tx] = src[(size_t)(e0 + ty + j) * Hc + n0 + tx];
    __syncthreads();
#pragma unroll
    for (int j = 0; j < 32; j += 8)
        dh[(size_t)(n0 + ty + j) * Ec + e0 + tx] = (_Float16)tile[tx][ty + j];
}

// ---------------------------------------------------------------------------
// gemm8_body: round-13 body VERBATIM (best measured for the projections).
// 256x256 tile, 8 waves (2x4, each 128x64), 512 threads, BK=32 slots,
// ring-3 LDS (96 KiB), ONE barrier per slot:
//   { 12 ds_read (bfr then af); stage(P+2) -> slot (P+2)%3 (4 gloads);
//     setprio(1); 32 MFMA; setprio(0); vmcnt(4); s_barrier }
// EPI: 0 = f16 out, N=2048: Q (gn<1024) / K (gn>=1024)
//      1 = f16 transposed store Vt[b][n][t]
// ---------------------------------------------------------------------------
template <int EPI>
DEV void gemm8_body(int bx, int by, int z,
                    const _Float16* __restrict__ Ah, const _Float16* __restrict__ Bh,
                    void* __restrict__ out0, void* __restrict__ out2,
                    int lda, int ldb, int nkt,
                    _Float16* sAb, _Float16* sBb) {
    const int tid = threadIdx.x;
    const int wave = tid >> 6, lane = tid & 63;
    const int lr = lane & 15, lk = lane >> 4;
    const int wm = wave >> 2, wn = wave & 3;  // 2 x 4 wave grid
    const int m0 = by * 256, n0 = bx * 256;

    const int so = (lane & 7) ^ (lane >> 3);
    const int strow = 2 * (lane >> 3) + (so >> 2);
    const int stcol = (so & 3) * 8;
    const size_t aoff0 = (size_t)(m0 + (wave * 2 + 0) * 16 + strow) * lda + stcol;
    const size_t aoff1 = (size_t)(m0 + (wave * 2 + 1) * 16 + strow) * lda + stcol;
    const size_t boff0 = (size_t)(n0 + (wave * 2 + 0) * 16 + strow) * ldb + stcol;
    const size_t boff1 = (size_t)(n0 + (wave * 2 + 1) * 16 + strow) * ldb + stcol;
    const int ld0 = (wave * 2 + 0) * 512, ld1 = (wave * 2 + 1) * 512;

    auto stage = [&](int sv, int slot) {
        const int kk = sv * 32;
        _Float16* dA = sAb + slot * SLOT;
        _Float16* dB = sBb + slot * SLOT;
        gload16(Ah + aoff0 + kk, dA + ld0);
        gload16(Ah + aoff1 + kk, dA + ld1);
        gload16(Bh + boff0 + kk, dB + ld0);
        gload16(Bh + boff1 + kk, dB + ld1);
    };

    f32x4 acc[8][4] = {};

    stage(0, 0);
    stage(1, 1);
    asm volatile("s_waitcnt vmcnt(4)" ::: "memory");
    __builtin_amdgcn_s_barrier();

    int rP = 0;
    for (int P = 0; P < nkt; ++P) {
        const _Float16* cA = sAb + rP * SLOT;
        const _Float16* cB = sBb + rP * SLOT;
        f16x8 af[8], bfr[4];
#pragma unroll
        for (int nj = 0; nj < 4; nj++)
            bfr[nj] = *reinterpret_cast<const f16x8*>(
                &cB[swz_off(wn * 64 + nj * 16 + lr, lk)]);
#pragma unroll
        for (int mi = 0; mi < 8; mi++)
            af[mi] = *reinterpret_cast<const f16x8*>(
                &cA[swz_off(wm * 128 + mi * 16 + lr, lk)]);

        int rs = rP + 2; if (rs >= 3) rs -= 3;
        if (P + 2 < nkt) stage(P + 2, rs);

        __builtin_amdgcn_s_setprio(1);
#pragma unroll
        for (int mi = 0; mi < 8; mi++)
#pragma unroll
            for (int nj = 0; nj < 4; nj++)
                acc[mi][nj] = mfma16(af[mi], bfr[nj], acc[mi][nj]);
        __builtin_amdgcn_s_setprio(0);

        if (P + 2 < nkt) {
            asm volatile("s_waitcnt vmcnt(4)" ::: "memory");
            __builtin_amdgcn_s_barrier();
        } else if (P + 1 < nkt) {
            asm volatile("s_waitcnt vmcnt(0)" ::: "memory");
            __builtin_amdgcn_s_barrier();
        }
        if (++rP == 3) rP = 0;
    }

#pragma unroll
    for (int mi = 0; mi < 8; mi++)
#pragma unroll
        for (int nj = 0; nj < 4; nj++) {
            const int gn = n0 + wn * 64 + nj * 16 + lr;
            if (EPI == 1) {
                const int gm0 = m0 + wm * 128 + mi * 16 + lk * 4;
                const int bb = gm0 >> 11, t = gm0 & (Tc - 1);
                f16x4 pk;
#pragma unroll
                for (int r = 0; r < 4; r++) pk[r] = (_Float16)acc[mi][nj][r];
                *reinterpret_cast<f16x4*>(
                    &((_Float16*)out0)[((size_t)(bb * Hc + gn)) * Tc + t]) = pk;
            } else {
                _Float16* od = (gn < 1024) ? (_Float16*)out0 : (_Float16*)out2;
                const int cc = gn & 1023;
#pragma unroll
                for (int r = 0; r < 4; r++) {
                    const int gm = m0 + wm * 128 + mi * 16 + lk * 4 + r;
                    od[(size_t)gm * Hc + cc] = (_Float16)acc[mi][nj][r];
                }
            }
        }
}

// ---------------------------------------------------------------------------
// gemm4_body: round-14 body VERBATIM — 128x256 tile, 4 waves (each 128x64),
// 256 threads, ring-3 (72 KiB -> 2 blocks/CU).  Used where load BALANCE
// dominates (energy/PV 128-row q-bands).  Same slot schedule, 6 gloads,
// vmcnt(6).
// EPI: 2 = f16 causal energy * 1/sqrt(dk)
//      3 = f32 row-major (PV), nkt = ((qband>>1)+1)*8
// ---------------------------------------------------------------------------
template <int EPI>
DEV void gemm4_body(int bx, int mt, int z,
                    const _Float16* __restrict__ Ah, const _Float16* __restrict__ Bh,
                    void* __restrict__ out0, const int* __restrict__ dkp,
                    int lda, int ldb, size_t aBS, size_t bBS, size_t oBS, int nkt,
                    _Float16* sAb, _Float16* sBb) {
    if (EPI == 3) nkt = ((mt >> 1) + 1) * 8;  // causal K extent (qband mt)

    Ah += (size_t)z * aBS;
    Bh += (size_t)z * bBS;

    const float scale = (EPI == 2) ? (1.0f / sqrtf((float)*dkp)) : 1.0f;

    const int tid = threadIdx.x;
    const int wave = tid >> 6, lane = tid & 63;
    const int lr = lane & 15, lk = lane >> 4;
    const int wn = wave;                // wave owns 128 x 64
    const int m0 = mt * 128, n0 = bx * 256;

    const int so = (lane & 7) ^ (lane >> 3);
    const int strow = 2 * (lane >> 3) + (so >> 2);
    const int stcol = (so & 3) * 8;
    const size_t aoff0 = (size_t)(m0 + (wave * 2 + 0) * 16 + strow) * lda + stcol;
    const size_t aoff1 = (size_t)(m0 + (wave * 2 + 1) * 16 + strow) * lda + stcol;
    size_t boff[4];
#pragma unroll
    for (int l = 0; l < 4; l++)
        boff[l] = (size_t)(n0 + (wave * 4 + l) * 16 + strow) * ldb + stcol;
    const int lda0 = (wave * 2 + 0) * 512, lda1 = (wave * 2 + 1) * 512;

    auto stage = [&](int sv, int slot) {
        const int kk = sv * 32;
        _Float16* dA = sAb + slot * SLOTA;
        _Float16* dB = sBb + slot * SLOT;
        gload16(Ah + aoff0 + kk, dA + lda0);
        gload16(Ah + aoff1 + kk, dA + lda1);
#pragma unroll
        for (int l = 0; l < 4; l++)
            gload16(Bh + boff[l] + kk, dB + (wave * 4 + l) * 512);
    };

    f32x4 acc[8][4] = {};

    stage(0, 0);
    stage(1, 1);
    asm volatile("s_waitcnt vmcnt(6)" ::: "memory");
    __builtin_amdgcn_s_barrier();

    int rP = 0;
    for (int P = 0; P < nkt; ++P) {
        const _Float16* cA = sAb + rP * SLOTA;
        const _Float16* cB = sBb + rP * SLOT;
        f16x8 af[8], bfr[4];
#pragma unroll
        for (int nj = 0; nj < 4; nj++)
            bfr[nj] = *reinterpret_cast<const f16x8*>(
                &cB[swz_off(wn * 64 + nj * 16 + lr, lk)]);
#pragma unroll
        for (int mi = 0; mi < 8; mi++)
            af[mi] = *reinterpret_cast<const f16x8*>(
                &cA[swz_off(mi * 16 + lr, lk)]);

        int rs = rP + 2; if (rs >= 3) rs -= 3;
        if (P + 2 < nkt) stage(P + 2, rs);

        __builtin_amdgcn_s_setprio(1);
#pragma unroll
        for (int mi = 0; mi < 8; mi++)
#pragma unroll
            for (int nj = 0; nj < 4; nj++)
                acc[mi][nj] = mfma16(af[mi], bfr[nj], acc[mi][nj]);
        __builtin_amdgcn_s_setprio(0);

        if (P + 2 < nkt) {
            asm volatile("s_waitcnt vmcnt(6)" ::: "memory");
            __builtin_amdgcn_s_barrier();
        } else if (P + 1 < nkt) {
            asm volatile("s_waitcnt vmcnt(0)" ::: "memory");
            __builtin_amdgcn_s_barrier();
        }
        if (++rP == 3) rP = 0;
    }

#pragma unroll
    for (int mi = 0; mi < 8; mi++)
#pragma unroll
        for (int nj = 0; nj < 4; nj++) {
            const int gn = n0 + wn * 64 + nj * 16 + lr;
#pragma unroll
            for (int r = 0; r < 4; r++) {
                const int gm = m0 + mi * 16 + lk * 4 + r;
                const float v = acc[mi][nj][r];
                if (EPI == 2) {
                    const float e = (gn > gm) ? -INFINITY : v * scale;
                    ((unsigned short*)out0)[(size_t)z * oBS + (size_t)gm * Tc + gn] =
                        f16bits(e);
                } else {
                    ((float*)out0)[(size_t)z * oBS + (size_t)gm * Hc + gn] = v;
                }
            }
        }
}

// ---------------------------------------------------------------------------
// k_qkv: round-13 config VERBATIM (best measured: 110.7 us).  QK-projection
// (512 blocks) + V-projection (256 blocks), 32 slots, 512 threads.
// launch_bounds(512,2): do NOT tighten (round 8: reg starvation = 9x).
// ---------------------------------------------------------------------------
__global__ __launch_bounds__(512, 2) void k_qkv(
        const _Float16* __restrict__ Xf, const _Float16* __restrict__ Wall,
        _Float16* __restrict__ Qf, _Float16* __restrict__ Kf,
        _Float16* __restrict__ Vt, const int* __restrict__ dkp) {
    __shared__ _Float16 sA[3][SLOT];  // 48 KiB
    __shared__ _Float16 sB[3][SLOT];  // 48 KiB
    const int i = blockIdx.x;
    if (i < 512) {
        const int w = (i & 7) * 64 + (i >> 3);  // bijective XCD chunking
        const int by = w >> 3, bx = w & 7;
        gemm8_body<0>(bx, by, 0, Xf, Wall, Qf, Kf, Ec, Ec, 32, sA[0], sB[0]);
    } else {
        const int j = i - 512;  // V proj: (4 x 64) tile grid
        gemm8_body<1>(j & 3, j >> 2, 0, Xf, Wall + (size_t)2048 * Ec,
                      Vt, nullptr, Ec, Ec, 32, sA[0], sB[0]);
    }
    (void)dkp;
}

// ---------------------------------------------------------------------------
// k_energy: 576 causal half-tiles (72 per batch: qband qb in [0,16) has
// (qb>>1)+1 k-tiles), 4-wave body, 2 blocks/CU -> wall ~1.5x a half-block
// round instead of the 8-wave 288-on-256 2-round wall.
// ---------------------------------------------------------------------------
__global__ __launch_bounds__(256, 2) void k_energy(
        const _Float16* __restrict__ Qf, const _Float16* __restrict__ Kf,
        unsigned short* __restrict__ S, const int* __restrict__ dkp) {
    __shared__ _Float16 sA[3][SLOTA];  // 24 KiB
    __shared__ _Float16 sB[3][SLOT];   // 48 KiB
    const int i = blockIdx.x;
    const int b = i / 72;
    int t = i - b * 72;
    int qb = 0;
    while (t >= (qb >> 1) + 1) { t -= (qb >> 1) + 1; qb++; }  // k-tile t <= qb>>1
    gemm4_body<2>(t, qb, b, Qf, Kf, S, dkp,
                  Hc, Hc, (size_t)Tc * Hc, (size_t)Tc * Hc, (size_t)Tc * Tc, 32,
                  sA[0], sB[0]);
}

// ---------------------------------------------------------------------------
// k_pv: 512 blocks (8 batches x 16 qbands x 4 bx), nkt = ((qb>>1)+1)*8.
// qbands enumerated in complementary pairs (qb, 15-qb) so co-resident block
// pairs sum to a constant 72 slots -> balanced at 2 blocks/CU.
// ---------------------------------------------------------------------------
__global__ __launch_bounds__(256, 2) void k_pv(
        const _Float16* __restrict__ S, const _Float16* __restrict__ Vt,
        float* __restrict__ out, const int* __restrict__ dkp) {
    __shared__ _Float16 sA[3][SLOTA];
    __shared__ _Float16 sB[3][SLOT];
    const int lin = blockIdx.x;
    const int b = lin >> 6;
    const int r = lin & 63;
    const int bx = r & 3, half = (r >> 2) & 1, pp = r >> 3;
    const int qb = half ? 15 - pp : pp;
    gemm4_body<3>(bx, qb, b, S, Vt, out, dkp,
                  Tc, Tc, (size_t)Tc * Tc, (size_t)Hc * Tc, (size_t)Tc * Hc, 0,
                  sA[0], sB[0]);
}

// ---------------------------------------------------------------------------
// softmax_k: one block per (b,q) row.  f16 logits in, f16 P out (in place).
// Threads beyond the tile-aligned causal extent skip loads/stores (PV never
// reads those cols) but participate in reductions.
// ---------------------------------------------------------------------------
__global__ __launch_bounds__(256) void softmax_k(unsigned short* __restrict__ S) {
    const int q = blockIdx.x & (Tc - 1);
    const int b = blockIdx.x >> 11;
    const int tid = threadIdx.x;
    const int c0 = tid * 8;
    const int limit = ((q >> 8) + 1) << 8;  // tile-aligned causal extent
    const bool active = c0 < limit;
    unsigned short* row = S + ((size_t)b * Tc + q) * Tc;

    float v[8];
    if (active) {
        uint4 raw = *reinterpret_cast<const uint4*>(row + c0);
        unsigned u[4] = {raw.x, raw.y, raw.z, raw.w};
#pragma unroll
        for (int p = 0; p < 4; p++) {
            v[2 * p]     = f16val((unsigned short)(u[p] & 0xFFFFu));
            v[2 * p + 1] = f16val((unsigned short)(u[p] >> 16));
        }
#pragma unroll
        for (int i = 0; i < 8; i++)
            if (c0 + i > q) v[i] = -INFINITY;
    } else {
#pragma unroll
        for (int i = 0; i < 8; i++) v[i] = -INFINITY;
    }

    float m = v[0];
#pragma unroll
    for (int i = 1; i < 8; i++) m = fmaxf(m, v[i]);
#pragma unroll
    for (int off = 1; off < 64; off <<= 1) m = fmaxf(m, __shfl_xor(m, off));
    __shared__ float red[4];
    if ((tid & 63) == 0) red[tid >> 6] = m;
    __syncthreads();
    m = fmaxf(fmaxf(red[0], red[1]), fmaxf(red[2], red[3]));

    float e[8], s = 0.f;
#pragma unroll
    for (int i = 0; i < 8; i++) {
        e[i] = __expf(v[i] - m);  // exp(-inf)=0
        s += e[i];
    }
#pragma unroll
    for (int off = 1; off < 64; off <<= 1) s += __shfl_xor(s, off);
    __syncthreads();
    if ((tid & 63) == 0) red[tid >> 6] = s;
    __syncthreads();
    s = red[0] + red[1] + red[2] + red[3];
    const float inv = 1.0f / s;

    if (active) {
        unsigned o[4];
#pragma unroll
        for (int p = 0; p < 4; p++) {
            unsigned short a = f16bits(e[2 * p] * inv);
            unsigned short bb = f16bits(e[2 * p + 1] * inv);
            o[p] = (unsigned)a | ((unsigned)bb << 16);
        }
        uint4 w; w.x = o[0]; w.y = o[1]; w.z = o[2]; w.w = o[3];
        *reinterpret_cast<uint4*>(row + c0) = w;
    }
}

// ---------------------------------------------------------------------------
extern "C" void kernel_launch(void* const* d_in, const int* in_sizes, int n_in,
                              void* d_out, int out_size, void* d_ws, size_t ws_size,
                              hipStream_t stream) {
    const float* x  = (const float*)d_in[0];
    const float* Wq = (const float*)d_in[1];
    const float* Wk = (const float*)d_in[2];
    const float* Wv = (const float*)d_in[3];
    const int*   dk = (const int*)d_in[4];
    float* out = (float*)d_out;
    char* ws = (char*)d_ws;

    const size_t SZ_XE = (size_t)Mc * Ec * 2;  // 32 MiB (f16 [16384][1024])
    const size_t SZ_W  = (size_t)Ec * Hc * 2;  // 2 MiB

    // Layout: persistent buffers first, prep buffers last so S can alias them.
    size_t o = 0;
    auto nxt = [&](size_t bytes) { void* p = ws + o; o += bytes; return p; };
    _Float16* Qf   = (_Float16*)nxt(SZ_XE);
    _Float16* Kf   = (_Float16*)nxt(SZ_XE);
    _Float16* Vt   = (_Float16*)nxt(SZ_XE);
    _Float16* Xf   = (_Float16*)nxt(SZ_XE);
    _Float16* Wall = (_Float16*)nxt(3 * SZ_W);  // [3072][1024] = Wq|Wk|Wv, transposed
    // S: all-batch f16 [8][2048][2048] = 64 MiB, aliases Xf+Wall+beyond
    // (Xf and Wall are dead once k_qkv completes; k_energy is stream-ordered).
    unsigned short* S = (unsigned short*)Xf;
    (void)ws_size; (void)in_sizes; (void)n_in; (void)out_size;

    prep_x<<<(Mc * Ec / 4 + 255) / 256, 256, 0, stream>>>(x, Xf, Mc * Ec);
    prep_w<<<dim3(32, 32, 3), 256, 0, stream>>>(Wq, Wk, Wv, Wall);

    // Q, K, V projections: single-term f16, K=1024 (round-13 config)
    k_qkv<<<768, 512, 0, stream>>>(Xf, Wall, Qf, Kf, Vt, dk);

    // energy: 576 causal half-tiles, f16 logits (4-wave, balanced)
    k_energy<<<576, 256, 0, stream>>>(Qf, Kf, (unsigned short*)S, dk);

    softmax_k<<<Bc * Tc, 256, 0, stream>>>((unsigned short*)S);

    // PV: complementary-paired qbands, nkt=((qb>>1)+1)*8 (4-wave, balanced)
    k_pv<<<512, 256, 0, stream>>>((const _Float16*)S, Vt, out, dk);
}

// Round 17
// 280.573 us; speedup vs baseline: 1.0693x; 1.0463x over previous
//
#include <hip/hip_runtime.h>

#define DEV __device__ __forceinline__

using f32x4 = __attribute__((ext_vector_type(4))) float;
using f16x8 = __attribute__((ext_vector_type(8))) _Float16;
using f16x4 = __attribute__((ext_vector_type(4))) _Float16;

constexpr int Bc = 8, Tc = 2048, Ec = 1024, Hc = 1024;
constexpr int Mc = Bc * Tc;    // 16384 total rows
constexpr int SLOT = 256 * 32; // elements per 16KB slice

DEV f32x4 mfma16(f16x8 a, f16x8 b, f32x4 c) {
    return __builtin_amdgcn_mfma_f32_16x16x32_f16(a, b, c, 0, 0, 0);
}
DEV unsigned short f16bits(float f) { return __builtin_bit_cast(unsigned short, (_Float16)f); }
DEV float f16val(unsigned short u) { return (float)__builtin_bit_cast(_Float16, u); }

// async global->LDS, 16B per lane. LDS dest must be wave-uniform base; HW adds lane*16.
DEV void gload16(const _Float16* g, _Float16* l) {
    __builtin_amdgcn_global_load_lds(
        (const __attribute__((address_space(1))) unsigned int*)g,
        (__attribute__((address_space(3))) unsigned int*)l, 16, 0, 0);
}

// Paired-row swizzled LDS slice layout (256x32 f16 = 16KB):
// LDS row r (128B) holds tile-rows {2r, 2r+1}; the 8 16B slots within row r
// are XOR-permuted by (r&7).  Verified 0 bank conflicts (rounds 5-16).
DEV int swz_off(int R, int lk) {
    return ((R >> 1) << 6) + ((((((R & 1) << 2) | lk) ^ ((R >> 1) & 7))) << 3);
}

// ---------------------------------------------------------------------------
// k_prep: merged prep_x (blocks [0,16384): f32 x -> f16) and prep_w
// (blocks [16384,19456): transpose W[e][n] -> Wall[n][e], f16).
// Wall[3072][1024]: rows [0,1024)=Wq, [1024,2048)=Wk, [2048,3072)=Wv.
// ---------------------------------------------------------------------------
__global__ __launch_bounds__(256) void k_prep(const float* __restrict__ x,
                                              const float* __restrict__ wq,
                                              const float* __restrict__ wk,
                                              const float* __restrict__ wv,
                                              _Float16* __restrict__ xf,
                                              _Float16* __restrict__ wall) {
    __shared__ float tile[32][33];
    const int i = blockIdx.x;
    if (i < 16384) {
        const int idx = (i * 256 + threadIdx.x) * 4;  // covers Mc*Ec exactly
        f32x4 v = *reinterpret_cast<const f32x4*>(x + idx);
        f16x4 h;
#pragma unroll
        for (int j = 0; j < 4; j++) h[j] = (_Float16)v[j];
        *reinterpret_cast<f16x4*>(xf + idx) = h;
    } else {
        const int j = i - 16384;
        const int z = j >> 10;          // 0..2
        const int rem = j & 1023;
        const int n0 = (rem & 31) * 32, e0 = (rem >> 5) * 32;
        const float* src = (z == 0) ? wq : (z == 1) ? wk : wv;
        _Float16* dh = wall + (size_t)z * 1024 * Ec;
        const int tx = threadIdx.x & 31, ty = threadIdx.x >> 5;  // 32 x 8
#pragma unroll
        for (int jj = 0; jj < 32; jj += 8)
            tile[ty + jj][tx] = src[(size_t)(e0 + ty + jj) * Hc + n0 + tx];
        __syncthreads();
#pragma unroll
        for (int jj = 0; jj < 32; jj += 8)
            dh[(size_t)(n0 + ty + jj) * Ec + e0 + tx] = (_Float16)tile[tx][ty + jj];
    }
}

// ---------------------------------------------------------------------------
// gemm_body: round-13 body VERBATIM (best measured: 110.7 us k_qkv, 287 us
// total).  256x256 tile, 8 waves (2x4, each 128x64), 512 threads, BK=32
// slots, ring-3 LDS (96 KiB), ONE barrier per slot:
//   { 12 ds_read (bfr then af); stage(P+2) -> slot (P+2)%3 (4 gloads);
//     setprio(1); 32 MFMA; setprio(0); vmcnt(4); s_barrier }
// Counted vmcnt(4): stage(P+2)'s 4 loads may stay in flight; stage(P+1)
// (issued in slot P-1) is proven complete at the slot exit.
// EPI: 0 = f16 out, N=2048: Q (gn<1024) / K (gn>=1024)
//      1 = f16 transposed store Vt[b][n][t]
//      2 = f16 causal energy * 1/sqrt(dk)
//      3 = f32 row-major (PV), nkt = (by+1)*8
// ---------------------------------------------------------------------------
template <int EPI>
DEV void gemm_body(int bx, int by, int z,
                   const _Float16* __restrict__ Ah, const _Float16* __restrict__ Bh,
                   void* __restrict__ out0, void* __restrict__ out2,
                   const int* __restrict__ dkp,
                   int lda, int ldb, size_t aBS, size_t bBS, size_t oBS, int nkt,
                   _Float16* sAb, _Float16* sBb) {
    if (EPI == 3) nkt = (by + 1) * 8;  // causal K extent (BK=32)

    Ah += (size_t)z * aBS;
    Bh += (size_t)z * bBS;

    const float scale = (EPI == 2) ? (1.0f / sqrtf((float)*dkp)) : 1.0f;

    const int tid = threadIdx.x;
    const int wave = tid >> 6, lane = tid & 63;
    const int lr = lane & 15, lk = lane >> 4;
    const int wm = wave >> 2, wn = wave & 3;  // 2 x 4 wave grid
    const int m0 = by * 256, n0 = bx * 256;

    // staging constants (inverse-swizzled global source, linear LDS dest):
    const int so = (lane & 7) ^ (lane >> 3);
    const int strow = 2 * (lane >> 3) + (so >> 2);
    const int stcol = (so & 3) * 8;
    const size_t aoff0 = (size_t)(m0 + (wave * 2 + 0) * 16 + strow) * lda + stcol;
    const size_t aoff1 = (size_t)(m0 + (wave * 2 + 1) * 16 + strow) * lda + stcol;
    const size_t boff0 = (size_t)(n0 + (wave * 2 + 0) * 16 + strow) * ldb + stcol;
    const size_t boff1 = (size_t)(n0 + (wave * 2 + 1) * 16 + strow) * ldb + stcol;
    const int ld0 = (wave * 2 + 0) * 512, ld1 = (wave * 2 + 1) * 512;

    auto stage = [&](int sv, int slot) {
        const int kk = sv * 32;
        _Float16* dA = sAb + slot * SLOT;
        _Float16* dB = sBb + slot * SLOT;
        gload16(Ah + aoff0 + kk, dA + ld0);
        gload16(Ah + aoff1 + kk, dA + ld1);
        gload16(Bh + boff0 + kk, dB + ld0);
        gload16(Bh + boff1 + kk, dB + ld1);
    };

    f32x4 acc[8][4] = {};

    // prologue: slots 0 and 1 in flight; gate slot 0 (allow slot 1's 4 loads)
    stage(0, 0);
    stage(1, 1);
    asm volatile("s_waitcnt vmcnt(4)" ::: "memory");
    __builtin_amdgcn_s_barrier();

    int rP = 0;  // P % 3
    for (int P = 0; P < nkt; ++P) {
        const _Float16* cA = sAb + rP * SLOT;
        const _Float16* cB = sBb + rP * SLOT;
        f16x8 af[8], bfr[4];

        // B frags first so the first MFMA's operands arrive earliest
#pragma unroll
        for (int nj = 0; nj < 4; nj++)
            bfr[nj] = *reinterpret_cast<const f16x8*>(
                &cB[swz_off(wn * 64 + nj * 16 + lr, lk)]);
#pragma unroll
        for (int mi = 0; mi < 8; mi++)
            af[mi] = *reinterpret_cast<const f16x8*>(
                &cA[swz_off(wm * 128 + mi * 16 + lr, lk)]);

        int rs = rP + 2; if (rs >= 3) rs -= 3;
        if (P + 2 < nkt) stage(P + 2, rs);

        __builtin_amdgcn_s_setprio(1);
#pragma unroll
        for (int mi = 0; mi < 8; mi++)
#pragma unroll
            for (int nj = 0; nj < 4; nj++)
                acc[mi][nj] = mfma16(af[mi], bfr[nj], acc[mi][nj]);
        __builtin_amdgcn_s_setprio(0);

        // slot-exit gate: stage(P+1) must be complete (counted; never 0 in
        // steady state).  Skip entirely on the last slot.
        if (P + 2 < nkt) {
            asm volatile("s_waitcnt vmcnt(4)" ::: "memory");
            __builtin_amdgcn_s_barrier();
        } else if (P + 1 < nkt) {
            asm volatile("s_waitcnt vmcnt(0)" ::: "memory");
            __builtin_amdgcn_s_barrier();
        }
        if (++rP == 3) rP = 0;
    }

#pragma unroll
    for (int mi = 0; mi < 8; mi++)
#pragma unroll
        for (int nj = 0; nj < 4; nj++) {
            const int gn = n0 + wn * 64 + nj * 16 + lr;
            if (EPI == 1) {
                const int gm0 = m0 + wm * 128 + mi * 16 + lk * 4;
                const int bb = gm0 >> 11, t = gm0 & (Tc - 1);
                f16x4 pk;
#pragma unroll
                for (int r = 0; r < 4; r++) pk[r] = (_Float16)acc[mi][nj][r];
                *reinterpret_cast<f16x4*>(
                    &((_Float16*)out0)[((size_t)(bb * Hc + gn)) * Tc + t]) = pk;
            } else if (EPI == 0) {
                _Float16* od = (gn < 1024) ? (_Float16*)out0 : (_Float16*)out2;
                const int cc = gn & 1023;
#pragma unroll
                for (int r = 0; r < 4; r++) {
                    const int gm = m0 + wm * 128 + mi * 16 + lk * 4 + r;
                    od[(size_t)gm * Hc + cc] = (_Float16)acc[mi][nj][r];
                }
            } else {
#pragma unroll
                for (int r = 0; r < 4; r++) {
                    const int gm = m0 + wm * 128 + mi * 16 + lk * 4 + r;
                    const float v = acc[mi][nj][r];
                    if (EPI == 2) {
                        const float e = (gn > gm) ? -INFINITY : v * scale;
                        ((unsigned short*)out0)[(size_t)z * oBS + (size_t)gm * Tc + gn] =
                            f16bits(e);
                    } else {
                        ((float*)out0)[(size_t)z * oBS + (size_t)gm * Hc + gn] = v;
                    }
                }
            }
        }
}

// ---------------------------------------------------------------------------
// k_qkv: QK-projection (512 blocks) + V-projection (256 blocks), 32 slots.
// launch_bounds(512,2): do NOT tighten — (512,4) spilled acc to scratch
// (round 8: 5.8 GB traffic, 9x slowdown).
// ---------------------------------------------------------------------------
__global__ __launch_bounds__(512, 2) void k_qkv(
        const _Float16* __restrict__ Xf, const _Float16* __restrict__ Wall,
        _Float16* __restrict__ Qf, _Float16* __restrict__ Kf,
        _Float16* __restrict__ Vt, const int* __restrict__ dkp) {
    __shared__ _Float16 sA[3][SLOT];  // 48 KiB
    __shared__ _Float16 sB[3][SLOT];  // 48 KiB
    const int i = blockIdx.x;
    if (i < 512) {
        // QK proj: bijective XCD chunking over the (8 x 64) tile grid
        const int w = (i & 7) * 64 + (i >> 3);
        const int by = w >> 3, bx = w & 7;
        gemm_body<0>(bx, by, 0, Xf, Wall, Qf, Kf, dkp,
                     Ec, Ec, 0, 0, 0, 32, sA[0], sB[0]);
    } else {
        const int j = i - 512;  // V proj: (4 x 64) tile grid
        gemm_body<1>(j & 3, j >> 2, 0, Xf, Wall + (size_t)2048 * Ec,
                     Vt, nullptr, dkp, Ec, Ec, 0, 0, 0, 32, sA[0], sB[0]);
    }
}

// ---------------------------------------------------------------------------
// k_energy: 288 causal tiles (36 per batch), single-term f16, 32 slots.
// ---------------------------------------------------------------------------
__global__ __launch_bounds__(512, 2) void k_energy(
        const _Float16* __restrict__ Qf, const _Float16* __restrict__ Kf,
        unsigned short* __restrict__ S, const int* __restrict__ dkp) {
    __shared__ _Float16 sA[3][SLOT];
    __shared__ _Float16 sB[3][SLOT];
    const int i = blockIdx.x;
    const int b = i / 36;
    int t = i - b * 36;
    int by = 0;
    while (t >= by + 1) { t -= by + 1; by++; }  // triangle decode: bx=t <= by
    gemm_body<2>(t, by, b, Qf, Kf, S, nullptr, dkp,
                 Hc, Hc, (size_t)Tc * Hc, (size_t)Tc * Hc, (size_t)Tc * Tc, 32,
                 sA[0], sB[0]);
}

// ---------------------------------------------------------------------------
// k_pv: PV, grid (4, 8, batch); nkt = (by+1)*8 inside body.  P is f16.
// ---------------------------------------------------------------------------
__global__ __launch_bounds__(512, 2) void k_pv(
        const _Float16* __restrict__ S, const _Float16* __restrict__ Vt,
        float* __restrict__ out, const int* __restrict__ dkp) {
    __shared__ _Float16 sA[3][SLOT];
    __shared__ _Float16 sB[3][SLOT];
    gemm_body<3>(blockIdx.x, blockIdx.y, blockIdx.z, S, Vt, out, nullptr, dkp,
                 Tc, Tc, (size_t)Tc * Tc, (size_t)Hc * Tc, (size_t)Tc * Hc, 0,
                 sA[0], sB[0]);
}

// ---------------------------------------------------------------------------
// softmax_w: ONE WAVE per row (4 rows per 256-thread block) — pure __shfl
// reductions, no LDS, no barriers.  f16 logits in, f16 P out (in place).
// Lane l, chunk c handles cols [c*512 + l*8, +8) (coalesced 16B/lane).
// Chunks beyond the tile-aligned causal extent skip load/store entirely
// (PV's K-extent is (q/256+1)*256, so those cols are never read).
// ---------------------------------------------------------------------------
__global__ __launch_bounds__(256) void softmax_w(unsigned short* __restrict__ S) {
    const int rid = blockIdx.x * 4 + (threadIdx.x >> 6);  // b*Tc + q
    const int lane = threadIdx.x & 63;
    const int q = rid & (Tc - 1);
    const int limit = ((q >> 8) + 1) << 8;  // tile-aligned causal extent
    unsigned short* row = S + (size_t)rid * Tc;

    float v[4][8];
    bool act[4];
#pragma unroll
    for (int c = 0; c < 4; c++) {
        const int c0 = c * 512 + lane * 8;
        act[c] = c0 < limit;  // limit % 256 == 0, so 8-groups are all-in/out
        if (act[c]) {
            uint4 raw = *reinterpret_cast<const uint4*>(row + c0);
            unsigned u[4] = {raw.x, raw.y, raw.z, raw.w};
#pragma unroll
            for (int p = 0; p < 4; p++) {
                v[c][2 * p]     = f16val((unsigned short)(u[p] & 0xFFFFu));
                v[c][2 * p + 1] = f16val((unsigned short)(u[p] >> 16));
            }
#pragma unroll
            for (int i = 0; i < 8; i++)
                if (c0 + i > q) v[c][i] = -INFINITY;
        } else {
#pragma unroll
            for (int i = 0; i < 8; i++) v[c][i] = -INFINITY;
        }
    }

    float m = -INFINITY;
#pragma unroll
    for (int c = 0; c < 4; c++)
#pragma unroll
        for (int i = 0; i < 8; i++) m = fmaxf(m, v[c][i]);
#pragma unroll
    for (int off = 1; off < 64; off <<= 1) m = fmaxf(m, __shfl_xor(m, off));

    float s = 0.f;
#pragma unroll
    for (int c = 0; c < 4; c++)
#pragma unroll
        for (int i = 0; i < 8; i++) {
            v[c][i] = __expf(v[c][i] - m);  // exp(-inf)=0
            s += v[c][i];
        }
#pragma unroll
    for (int off = 1; off < 64; off <<= 1) s += __shfl_xor(s, off);
    const float inv = 1.0f / s;

#pragma unroll
    for (int c = 0; c < 4; c++) {
        if (!act[c]) continue;
        const int c0 = c * 512 + lane * 8;
        unsigned o[4];
#pragma unroll
        for (int p = 0; p < 4; p++) {
            unsigned short a = f16bits(v[c][2 * p] * inv);
            unsigned short bb = f16bits(v[c][2 * p + 1] * inv);
            o[p] = (unsigned)a | ((unsigned)bb << 16);
        }
        uint4 w; w.x = o[0]; w.y = o[1]; w.z = o[2]; w.w = o[3];
        *reinterpret_cast<uint4*>(row + c0) = w;
    }
}

// ---------------------------------------------------------------------------
extern "C" void kernel_launch(void* const* d_in, const int* in_sizes, int n_in,
                              void* d_out, int out_size, void* d_ws, size_t ws_size,
                              hipStream_t stream) {
    const float* x  = (const float*)d_in[0];
    const float* Wq = (const float*)d_in[1];
    const float* Wk = (const float*)d_in[2];
    const float* Wv = (const float*)d_in[3];
    const int*   dk = (const int*)d_in[4];
    float* out = (float*)d_out;
    char* ws = (char*)d_ws;

    const size_t SZ_XE = (size_t)Mc * Ec * 2;  // 32 MiB (f16 [16384][1024])
    const size_t SZ_W  = (size_t)Ec * Hc * 2;  // 2 MiB

    // Layout: persistent buffers first, prep buffers last so S can alias them.
    size_t o = 0;
    auto nxt = [&](size_t bytes) { void* p = ws + o; o += bytes; return p; };
    _Float16* Qf   = (_Float16*)nxt(SZ_XE);
    _Float16* Kf   = (_Float16*)nxt(SZ_XE);
    _Float16* Vt   = (_Float16*)nxt(SZ_XE);
    _Float16* Xf   = (_Float16*)nxt(SZ_XE);
    _Float16* Wall = (_Float16*)nxt(3 * SZ_W);  // [3072][1024] = Wq|Wk|Wv, transposed
    // S: all-batch f16 [8][2048][2048] = 64 MiB, aliases Xf+Wall+beyond
    // (Xf and Wall are dead once k_qkv completes; k_energy is stream-ordered).
    unsigned short* S = (unsigned short*)Xf;
    (void)ws_size; (void)in_sizes; (void)n_in; (void)out_size;

    // merged prep: x->f16 (16384 blocks) + W transpose (3072 blocks)
    k_prep<<<19456, 256, 0, stream>>>(x, Wq, Wk, Wv, Xf, Wall);

    // Q, K, V projections: single-term f16, K=1024 (round-13 config)
    k_qkv<<<768, 512, 0, stream>>>(Xf, Wall, Qf, Kf, Vt, dk);

    // energy: 288 causal tiles, f16 logits (round-13 config)
    k_energy<<<288, 512, 0, stream>>>(Qf, Kf, (unsigned short*)S, dk);

    // softmax: one wave per row, 4 rows/block
    softmax_w<<<Bc * Tc / 4, 256, 0, stream>>>((unsigned short*)S);

    // PV: nkt=(by+1)*8 per tile (P beyond causal edge is 0)
    k_pv<<<dim3(4, 8, Bc), 512, 0, stream>>>((const _Float16*)S, Vt, out, dk);
}